// Round 2
// 1950.752 us; speedup vs baseline: 2.7648x; 2.7648x over previous
//
#include <hip/hip_runtime.h>
#include <hip/hip_bf16.h>

#define BB 16384
#define NN 54
#define TT 80
#define HH 48
#define PH 80
#define SHH 32
#define AA 397
#define EPSF 1e-5f

typedef __hip_bfloat16 bf16;

__device__ __forceinline__ float tof(float x){ return x; }
__device__ __forceinline__ float tof(bf16 x){ return __bfloat162float(x); }
__device__ __forceinline__ void stor(float* p, float v){ *p = v; }
__device__ __forceinline__ void stor(bf16* p, float v){ *p = __float2bfloat16(v); }

// mish(x) = x * tanh(softplus(x)) = x * w/(w+2), w = e*(2+e), e = exp(x)
__device__ __forceinline__ float mishf(float x){
    float e = __expf(fminf(x, 15.f));
    float w = e * (2.f + e);
    return x * w / (w + 2.f);
}

struct P30 { const void* a[30]; };

// ---- packed-weight workspace layout (fp32 element offsets) ----
#define OFF_WtT   0                     // [80][128] tn-part weights: sett|city|road|0
#define OFF_WnT   (OFF_WtT + 80*128)    // [48][128] node-part: sett|city|road_src|road_dst
#define OFF_B1P   (OFF_WnT + 48*128)    // [128] layer-1 biases (dst cols = 0)
#define OFF_WRT   (OFF_B1P + 128)       // [80][32] robber tn-part
#define OFF_WRN   (OFF_WRT + 80*32)     // [48][32] robber tile-part
#define OFF_RB1   (OFF_WRN + 48*32)     // [32] rob1_b
#define OFF_W2P   (OFF_RB1 + 32)        // [96] sett2_w|city2_w|road2_w
#define OFF_ROB2  (OFF_W2P + 96)        // [5][32] rob2_w
#define OFF_B2S   (OFF_ROB2 + 160)      // [8] sett2_b,city2_b,road2_b,rob2_b[5]
#define OFF_LNW   (OFF_B2S + 8)         // [48] ln_n_w
#define OFF_LNB   (OFF_LNW + 48)        // [48] ln_n_b
#define OFF_B2G   (OFF_LNB + 48)        // [122] gfc2_b at surviving cols
#define OFF_WG1T  (OFF_B2G + 122)       // [80][80] gfc1_w transposed
#define OFF_B1G   (OFF_WG1T + 80*80)    // [80] gfc1_b
#define PK_TOTAL  (OFF_B1G + 80)

// Runtime dtype probe: bf16 data has sane exponents at EVEN element indices;
// fp32 data read as bf16 has uniform-random exponents there.
__global__ void k_detect(const unsigned short* tr, int* flag){
    if (threadIdx.x == 0 && blockIdx.x == 0){
        int good = 0;
        for (int i = 0; i < 1024; i += 2){
            int e = (tr[i] >> 7) & 0xFF;
            if (e >= 117 && e <= 137) good++;
        }
        *flag = (good > 256) ? 1 : 0;   // 1 = bf16, 0 = float32
    }
}

// ---------------- K0: pack/transpose all head weights to fp32 ----------------
template<typename T>
__device__ void prep_body(P30 p, float* pk){
    const T* sett1_w=(const T*)p.a[14]; const T* sett1_b=(const T*)p.a[15];
    const T* sett2_w=(const T*)p.a[16]; const T* sett2_b=(const T*)p.a[17];
    const T* city1_w=(const T*)p.a[18]; const T* city1_b=(const T*)p.a[19];
    const T* city2_w=(const T*)p.a[20]; const T* city2_b=(const T*)p.a[21];
    const T* road1_w=(const T*)p.a[22]; const T* road1_b=(const T*)p.a[23];
    const T* road2_w=(const T*)p.a[24]; const T* road2_b=(const T*)p.a[25];
    const T* rob1_w =(const T*)p.a[26]; const T* rob1_b =(const T*)p.a[27];
    const T* rob2_w =(const T*)p.a[28]; const T* rob2_b =(const T*)p.a[29];
    const T* gfc1_w =(const T*)p.a[8];  const T* gfc1_b =(const T*)p.a[9];
    const T* gfc2_b =(const T*)p.a[13];
    const T* ln_n_w =(const T*)p.a[6];  const T* ln_n_b =(const T*)p.a[7];

    int gid = blockIdx.x*blockDim.x + threadIdx.x;
    int gsz = gridDim.x*blockDim.x;

    for (int i=gid; i<80*128; i+=gsz){ int k=i>>7, j=i&127; float v;
        if (j<32)      v = tof(sett1_w[j*128+k]);
        else if (j<64) v = tof(city1_w[(j-32)*128+k]);
        else if (j<96) v = tof(road1_w[(j-64)*176+k]);
        else           v = 0.f;
        pk[OFF_WtT+i]=v; }
    for (int i=gid; i<48*128; i+=gsz){ int k=i>>7, j=i&127; float v;
        if (j<32)      v = tof(sett1_w[j*128+80+k]);
        else if (j<64) v = tof(city1_w[(j-32)*128+80+k]);
        else if (j<96) v = tof(road1_w[(j-64)*176+80+k]);
        else           v = tof(road1_w[(j-96)*176+128+k]);
        pk[OFF_WnT+i]=v; }
    for (int i=gid; i<128; i+=gsz){ float v;
        if (i<32) v=tof(sett1_b[i]); else if (i<64) v=tof(city1_b[i-32]);
        else if (i<96) v=tof(road1_b[i-64]); else v=0.f;
        pk[OFF_B1P+i]=v; }
    for (int i=gid; i<80*32; i+=gsz){ int k=i>>5, h=i&31; pk[OFF_WRT+i]=tof(rob1_w[h*128+k]); }
    for (int i=gid; i<48*32; i+=gsz){ int k=i>>5, h=i&31; pk[OFF_WRN+i]=tof(rob1_w[h*128+80+k]); }
    for (int i=gid; i<32; i+=gsz) pk[OFF_RB1+i]=tof(rob1_b[i]);
    for (int i=gid; i<96; i+=gsz){ float v;
        if (i<32) v=tof(sett2_w[i]); else if (i<64) v=tof(city2_w[i-32]); else v=tof(road2_w[i-64]);
        pk[OFF_W2P+i]=v; }
    for (int i=gid; i<160; i+=gsz) pk[OFF_ROB2+i]=tof(rob2_w[i]);
    for (int i=gid; i<8; i+=gsz){ float v;
        if (i==0) v=tof(sett2_b[0]); else if (i==1) v=tof(city2_b[0]);
        else if (i==2) v=tof(road2_b[0]); else v=tof(rob2_b[i-3]);
        pk[OFF_B2S+i]=v; }
    for (int i=gid; i<48; i+=gsz){ pk[OFF_LNW+i]=tof(ln_n_w[i]); pk[OFF_LNB+i]=tof(ln_n_b[i]); }
    for (int i=gid; i<122; i+=gsz){ int col = (i<5)? i : (280+i-5); pk[OFF_B2G+i]=tof(gfc2_b[col]); }
    for (int i=gid; i<80*80; i+=gsz){ int k=i/80, j=i%80; pk[OFF_WG1T+i]=tof(gfc1_w[j*80+k]); }
    for (int i=gid; i<80; i+=gsz) pk[OFF_B1G+i]=tof(gfc1_b[i]);
}

__global__ void k_prep(P30 p, float* pk, const int* __restrict__ flag){
    if (*flag) prep_body<bf16>(p, pk); else prep_body<float>(p, pk);
}

// ---------------- K1: trunk layernorm + gfc1 (coalesced via Wg1T) ----------------
template<typename T>
__device__ __forceinline__ void tn_h_body(
        const T* __restrict__ trunk, const T* __restrict__ lw, const T* __restrict__ lb,
        const float* __restrict__ Wg1T, const float* __restrict__ b1g,
        float* __restrict__ tn_out, float* __restrict__ h_out, float (*s_tn)[TT]){
    int wave = threadIdx.x >> 6, lane = threadIdx.x & 63;
    int row  = blockIdx.x * 4 + wave;
    const T* tr = trunk + row * TT;
    float x0 = (lane < TT)      ? tof(tr[lane])      : 0.f;
    float x1 = (lane + 64 < TT) ? tof(tr[lane + 64]) : 0.f;
    float s = x0 + x1;
    for (int m = 32; m; m >>= 1) s += __shfl_xor(s, m, 64);
    float mu = s / TT;
    float d0 = (lane < TT)      ? (x0 - mu) : 0.f;
    float d1 = (lane + 64 < TT) ? (x1 - mu) : 0.f;
    float v = d0*d0 + d1*d1;
    for (int m = 32; m; m >>= 1) v += __shfl_xor(v, m, 64);
    float rstd = rsqrtf(v / TT + EPSF);
    if (lane < TT){
        float t = d0 * rstd * tof(lw[lane]) + tof(lb[lane]);
        s_tn[wave][lane] = t;
        tn_out[row*TT + lane] = t;
    }
    if (lane + 64 < TT){
        int i = lane + 64;
        float t = d1 * rstd * tof(lw[i]) + tof(lb[i]);
        s_tn[wave][i] = t;
        tn_out[row*TT + i] = t;
    }
    __syncthreads();
    for (int j = lane; j < PH; j += 64){
        float acc = b1g[j];
        #pragma unroll 8
        for (int k = 0; k < TT; ++k) acc += s_tn[wave][k] * Wg1T[k*PH + j];
        h_out[row*PH + j] = acc;
    }
}

__global__ __launch_bounds__(256) void k_tn_h(P30 p, const float* pk, float* tn_out,
                                              float* h_out, const int* __restrict__ flag){
    __shared__ float s_tn[4][TT];
    const float* Wg1T = pk + OFF_WG1T;
    const float* b1g  = pk + OFF_B1G;
    if (*flag)
        tn_h_body<bf16>((const bf16*)p.a[0], (const bf16*)p.a[4], (const bf16*)p.a[5],
                        Wg1T, b1g, tn_out, h_out, s_tn);
    else
        tn_h_body<float>((const float*)p.a[0], (const float*)p.a[4], (const float*)p.a[5],
                         Wg1T, b1g, tn_out, h_out, s_tn);
}

// ---------------- K2: batchnorm stats over B ----------------
template<typename T>
__device__ __forceinline__ void bnstats_body(
        const float* __restrict__ h, const T* __restrict__ bw, const T* __restrict__ bb,
        float* __restrict__ scale, float* __restrict__ shift){
    __shared__ float ss[256], sq[256];
    int f = blockIdx.x;
    float s = 0.f, q = 0.f;
    for (int b = threadIdx.x; b < BB; b += 256){
        float x = h[b*PH + f];
        s += x; q += x*x;
    }
    ss[threadIdx.x] = s; sq[threadIdx.x] = q;
    __syncthreads();
    for (int m = 128; m; m >>= 1){
        if ((int)threadIdx.x < m){
            ss[threadIdx.x] += ss[threadIdx.x + m];
            sq[threadIdx.x] += sq[threadIdx.x + m];
        }
        __syncthreads();
    }
    if (threadIdx.x == 0){
        float mu  = ss[0] / BB;
        float var = sq[0] / BB - mu*mu;
        float sc  = rsqrtf(var + EPSF) * tof(bw[f]);
        scale[f] = sc;
        shift[f] = tof(bb[f]) - mu * sc;
    }
}

__global__ __launch_bounds__(256) void k_bnstats(P30 p, const float* h,
                                                 float* scale, float* shift,
                                                 const int* __restrict__ flag){
    if (*flag) bnstats_body<bf16>(h, (const bf16*)p.a[10], (const bf16*)p.a[11], scale, shift);
    else       bnstats_body<float>(h, (const float*)p.a[10], (const float*)p.a[11], scale, shift);
}

// ---------------- K3: node LN + factored projections + all heads ----------------
struct HeadsSmem {
    float s_tn[TT];          // trunk LN row
    float s_mish[PH];        // mish(bn(h)) for the global head
    float s_nnT[HH][56];     // node LN, TRANSPOSED [k][n], stride 56
    float s_tp[128];         // tn-part projections + bias (sett|city|road|0)
    float s_np[NN*128];      // node-part projections [n][128]
    float s_rtp[32];         // robber tn-part + bias
    float s_trp[19*32];      // robber tile projections
};

// Each thread owns output column j; acts are wave-broadcast LDS reads, weights coalesced.
template<int C0, int CH>
__device__ __forceinline__ void proj_chunk(int j, const float* __restrict__ WnT,
        const float (* __restrict__ s_nnT)[56], float* __restrict__ s_np){
    float acc[CH];
    #pragma unroll
    for (int i = 0; i < CH; ++i) acc[i] = 0.f;
    #pragma unroll 4
    for (int k = 0; k < HH; ++k){
        float wv = WnT[k*128 + j];
        #pragma unroll
        for (int i = 0; i < CH; ++i) acc[i] += s_nnT[k][C0+i] * wv;
    }
    #pragma unroll
    for (int i = 0; i < CH; ++i) s_np[(C0+i)*128 + j] = acc[i];
}

template<typename T>
__device__ void heads_body(HeadsSmem& sm,
        const T* __restrict__ node_emb, const int* __restrict__ road_pairs,
        const int* __restrict__ tile_nodes, const T* __restrict__ gfc2_w,
        const float* __restrict__ tn_g, const float* __restrict__ hbuf,
        const float* __restrict__ scale, const float* __restrict__ shift,
        const float* __restrict__ pk, T* __restrict__ out){
    const float* WtT  = pk + OFF_WtT;
    const float* WnT  = pk + OFF_WnT;
    const float* b1p  = pk + OFF_B1P;
    const float* WrtT = pk + OFF_WRT;
    const float* WrnT = pk + OFF_WRN;
    const float* rb1  = pk + OFF_RB1;
    const float* w2p  = pk + OFF_W2P;
    const float* rob2p= pk + OFF_ROB2;
    const float* b2s  = pk + OFF_B2S;
    const float* lnw  = pk + OFF_LNW;
    const float* lnb  = pk + OFF_LNB;
    const float* b2g  = pk + OFF_B2G;

    int row = blockIdx.x, tid = threadIdx.x;
    int wave = tid >> 6, lane = tid & 63;

    // ---- phase 0: stage tn row, global-head mish, node LN (transposed write) ----
    if (tid < TT) sm.s_tn[tid] = tn_g[row*TT + tid];
    if (tid >= 128 && tid < 128 + PH){
        int t = tid - 128;
        sm.s_mish[t] = mishf(hbuf[row*PH + t] * scale[t] + shift[t]);
    }
    for (int n = wave; n < NN; n += 4){
        const T* ne = node_emb + ((size_t)row*NN + n)*HH;
        float x = (lane < HH) ? tof(ne[lane]) : 0.f;
        float s = x, q = x*x;
        for (int m = 32; m; m >>= 1){ s += __shfl_xor(s, m, 64); q += __shfl_xor(q, m, 64); }
        float mu = s / HH, var = q / HH - mu*mu;
        float rstd = rsqrtf(fmaxf(var, 0.f) + EPSF);
        if (lane < HH) sm.s_nnT[lane][n] = (x - mu)*rstd*lnw[lane] + lnb[lane];
    }
    __syncthreads();

    // ---- stage 1: factored projections ----
    if (tid < 128){
        int j = tid;
        float tp = b1p[j];
        #pragma unroll 8
        for (int k = 0; k < TT; ++k) tp += sm.s_tn[k] * WtT[k*128 + j];
        sm.s_tp[j] = tp;
        proj_chunk<0,32>(j, WnT, sm.s_nnT, sm.s_np);          // nodes 0..31
    } else {
        int j = tid - 128;
        proj_chunk<32,22>(j, WnT, sm.s_nnT, sm.s_np);         // nodes 32..53
        if (j < 32){
            float rp = rb1[j];
            #pragma unroll 8
            for (int k = 0; k < TT; ++k) rp += sm.s_tn[k] * WrtT[k*32 + j];
            sm.s_rtp[j] = rp;
        }
        int h = j & 31, g = j >> 5;
        for (int t = g; t < 19; t += 4){
            int nd0 = tile_nodes[t*6+0], nd1 = tile_nodes[t*6+1], nd2 = tile_nodes[t*6+2];
            int nd3 = tile_nodes[t*6+3], nd4 = tile_nodes[t*6+4], nd5 = tile_nodes[t*6+5];
            float acc = 0.f;
            #pragma unroll 4
            for (int k = 0; k < HH; ++k){
                float tk = sm.s_nnT[k][nd0] + sm.s_nnT[k][nd1] + sm.s_nnT[k][nd2]
                         + sm.s_nnT[k][nd3] + sm.s_nnT[k][nd4] + sm.s_nnT[k][nd5];
                acc += tk * WrnT[k*32 + h];
            }
            sm.s_trp[t*32 + h] = acc * (1.f/6.f);
        }
    }
    __syncthreads();

    // ---- stage 2: 321 tasks (108 sett/city + 72 road + 19 robber + 122 global) ----
    int half = tid >> 5, hl = tid & 31;
    T* orow = out + (size_t)row*AA;
    for (int task = half; task < 321; task += 8){
        if (task < 108){
            bool city = (task >= 54);
            int n = city ? task - 54 : task;
            int base = city ? 32 : 0;
            float hid = sm.s_tp[base + hl] + sm.s_np[n*128 + base + hl];
            float val = mishf(hid) * w2p[base + hl];
            for (int m = 16; m; m >>= 1) val += __shfl_xor(val, m, 64);
            if (hl == 0) stor(orow + (city ? 59 : 5) + n, val + b2s[city ? 1 : 0]);
        } else if (task < 180){
            int r = task - 108;
            int srcn = road_pairs[2*r], dstn = road_pairs[2*r + 1];
            float hid = sm.s_tp[64 + hl] + sm.s_np[srcn*128 + 64 + hl]
                                         + sm.s_np[dstn*128 + 96 + hl];
            float val = mishf(hid) * w2p[64 + hl];
            for (int m = 16; m; m >>= 1) val += __shfl_xor(val, m, 64);
            if (hl == 0) stor(orow + 113 + r, val + b2s[2]);
        } else if (task < 199){
            int t2 = task - 180;
            float hid = sm.s_rtp[hl] + sm.s_trp[t2*32 + hl];
            float mv = mishf(hid);
            #pragma unroll
            for (int k5 = 0; k5 < 5; ++k5){
                float val = mv * rob2p[k5*32 + hl];
                for (int m = 16; m; m >>= 1) val += __shfl_xor(val, m, 64);
                if (hl == 0) stor(orow + 185 + t2*5 + k5, val + b2s[3 + k5]);
            }
        } else {
            int c = task - 199;
            int col = (c < 5) ? c : (280 + c - 5);
            const T* wr = gfc2_w + col*PH;
            float acc = 0.f;
            for (int k = hl; k < PH; k += 32) acc += sm.s_mish[k] * tof(wr[k]);
            for (int m = 16; m; m >>= 1) acc += __shfl_xor(acc, m, 64);
            if (hl == 0) stor(orow + col, acc + b2g[c]);
        }
    }
}

__global__ __launch_bounds__(256) void k_heads(P30 p, const float* tn_g, const float* hbuf,
                                               const float* scale, const float* shift,
                                               const float* pk, void* out,
                                               const int* __restrict__ flag){
    __shared__ HeadsSmem sm;
    if (*flag)
        heads_body<bf16>(sm, (const bf16*)p.a[1], (const int*)p.a[2], (const int*)p.a[3],
                         (const bf16*)p.a[12], tn_g, hbuf, scale, shift, pk, (bf16*)out);
    else
        heads_body<float>(sm, (const float*)p.a[1], (const int*)p.a[2], (const int*)p.a[3],
                          (const float*)p.a[12], tn_g, hbuf, scale, shift, pk, (float*)out);
}

extern "C" void kernel_launch(void* const* d_in, const int* in_sizes, int n_in,
                              void* d_out, int out_size, void* d_ws, size_t ws_size,
                              hipStream_t stream){
    P30 p;
    for (int i = 0; i < 30; ++i) p.a[i] = d_in[i];

    int*   flag  = (int*)d_ws;
    float* h     = (float*)((char*)d_ws + 256);     // B*PH floats
    float* tn    = h + (size_t)BB*PH;               // B*T floats
    float* scale = tn + (size_t)BB*TT;              // PH
    float* shift = scale + PH;                      // PH
    float* pk    = shift + PH;                      // PK_TOTAL floats of packed weights

    k_detect<<<1, 64, 0, stream>>>((const unsigned short*)d_in[0], flag);
    k_prep<<<64, 256, 0, stream>>>(p, pk, flag);
    k_tn_h<<<BB/4, 256, 0, stream>>>(p, pk, tn, h, flag);
    k_bnstats<<<PH, 256, 0, stream>>>(p, h, scale, shift, flag);
    k_heads<<<BB, 256, 0, stream>>>(p, tn, h, scale, shift, pk, d_out, flag);
}

// Round 3
// 1351.056 us; speedup vs baseline: 3.9920x; 1.4439x over previous
//
#include <hip/hip_runtime.h>
#include <hip/hip_bf16.h>

#define BB 16384
#define NN 54
#define TT 80
#define HH 48
#define PH 80
#define SHH 32
#define AA 397
#define EPSF 1e-5f

typedef __hip_bfloat16 bf16;

__device__ __forceinline__ float tof(float x){ return x; }
__device__ __forceinline__ float tof(bf16 x){ return __bfloat162float(x); }
__device__ __forceinline__ void stor(float* p, float v){ *p = v; }
__device__ __forceinline__ void stor(bf16* p, float v){ *p = __float2bfloat16(v); }

// mish(x) = x * tanh(softplus(x)) = x * w/(w+2), w = e*(2+e), e = exp(x)
__device__ __forceinline__ float mishf(float x){
    float e = __expf(fminf(x, 15.f));
    float w = e * (2.f + e);
    return x * w / (w + 2.f);
}

struct P30 { const void* a[30]; };

// ---- packed-weight workspace layout (fp32 element offsets) ----
#define OFF_WtT   0                     // [80][128] tn-part weights: sett|city|road|0
#define OFF_WnT   (OFF_WtT + 80*128)    // [48][128] node-part: sett|city|road_src|road_dst
#define OFF_B1P   (OFF_WnT + 48*128)    // [128] layer-1 biases (dst cols = 0)
#define OFF_WRT   (OFF_B1P + 128)       // [80][32] robber tn-part
#define OFF_WRN   (OFF_WRT + 80*32)     // [48][32] robber tile-part
#define OFF_RB1   (OFF_WRN + 48*32)     // [32] rob1_b
#define OFF_W2P   (OFF_RB1 + 32)        // [96] sett2_w|city2_w|road2_w
#define OFF_ROB2  (OFF_W2P + 96)        // [5][32] rob2_w
#define OFF_B2S   (OFF_ROB2 + 160)      // [8] sett2_b,city2_b,road2_b,rob2_b[5]
#define OFF_LNW   (OFF_B2S + 8)         // [48] ln_n_w
#define OFF_LNB   (OFF_LNW + 48)        // [48] ln_n_b
#define OFF_B2G   (OFF_LNB + 48)        // [122] gfc2_b at surviving cols
#define OFF_WG1T  (OFF_B2G + 122)       // [80][80] gfc1_w transposed
#define OFF_B1G   (OFF_WG1T + 80*80)    // [80] gfc1_b
#define OFF_WG2T  (OFF_B1G + 80)        // [80][122] gfc2_w transposed, surviving cols
#define PK_TOTAL  (OFF_WG2T + 80*122)

// Runtime dtype probe: bf16 data has sane exponents at EVEN element indices;
// fp32 data read as bf16 has uniform-random exponents there.
__global__ void k_detect(const unsigned short* tr, int* flag){
    if (threadIdx.x == 0 && blockIdx.x == 0){
        int good = 0;
        for (int i = 0; i < 1024; i += 2){
            int e = (tr[i] >> 7) & 0xFF;
            if (e >= 117 && e <= 137) good++;
        }
        *flag = (good > 256) ? 1 : 0;   // 1 = bf16, 0 = float32
    }
}

// ---------------- K0: pack/transpose all head weights to fp32 ----------------
template<typename T>
__device__ void prep_body(P30 p, float* pk){
    const T* sett1_w=(const T*)p.a[14]; const T* sett1_b=(const T*)p.a[15];
    const T* sett2_w=(const T*)p.a[16]; const T* sett2_b=(const T*)p.a[17];
    const T* city1_w=(const T*)p.a[18]; const T* city1_b=(const T*)p.a[19];
    const T* city2_w=(const T*)p.a[20]; const T* city2_b=(const T*)p.a[21];
    const T* road1_w=(const T*)p.a[22]; const T* road1_b=(const T*)p.a[23];
    const T* road2_w=(const T*)p.a[24]; const T* road2_b=(const T*)p.a[25];
    const T* rob1_w =(const T*)p.a[26]; const T* rob1_b =(const T*)p.a[27];
    const T* rob2_w =(const T*)p.a[28]; const T* rob2_b =(const T*)p.a[29];
    const T* gfc1_w =(const T*)p.a[8];  const T* gfc1_b =(const T*)p.a[9];
    const T* gfc2_w =(const T*)p.a[12]; const T* gfc2_b =(const T*)p.a[13];
    const T* ln_n_w =(const T*)p.a[6];  const T* ln_n_b =(const T*)p.a[7];

    int gid = blockIdx.x*blockDim.x + threadIdx.x;
    int gsz = gridDim.x*blockDim.x;

    for (int i=gid; i<80*128; i+=gsz){ int k=i>>7, j=i&127; float v;
        if (j<32)      v = tof(sett1_w[j*128+k]);
        else if (j<64) v = tof(city1_w[(j-32)*128+k]);
        else if (j<96) v = tof(road1_w[(j-64)*176+k]);
        else           v = 0.f;
        pk[OFF_WtT+i]=v; }
    for (int i=gid; i<48*128; i+=gsz){ int k=i>>7, j=i&127; float v;
        if (j<32)      v = tof(sett1_w[j*128+80+k]);
        else if (j<64) v = tof(city1_w[(j-32)*128+80+k]);
        else if (j<96) v = tof(road1_w[(j-64)*176+80+k]);
        else           v = tof(road1_w[(j-96)*176+128+k]);
        pk[OFF_WnT+i]=v; }
    for (int i=gid; i<128; i+=gsz){ float v;
        if (i<32) v=tof(sett1_b[i]); else if (i<64) v=tof(city1_b[i-32]);
        else if (i<96) v=tof(road1_b[i-64]); else v=0.f;
        pk[OFF_B1P+i]=v; }
    for (int i=gid; i<80*32; i+=gsz){ int k=i>>5, h=i&31; pk[OFF_WRT+i]=tof(rob1_w[h*128+k]); }
    for (int i=gid; i<48*32; i+=gsz){ int k=i>>5, h=i&31; pk[OFF_WRN+i]=tof(rob1_w[h*128+80+k]); }
    for (int i=gid; i<32; i+=gsz) pk[OFF_RB1+i]=tof(rob1_b[i]);
    for (int i=gid; i<96; i+=gsz){ float v;
        if (i<32) v=tof(sett2_w[i]); else if (i<64) v=tof(city2_w[i-32]); else v=tof(road2_w[i-64]);
        pk[OFF_W2P+i]=v; }
    for (int i=gid; i<160; i+=gsz) pk[OFF_ROB2+i]=tof(rob2_w[i]);
    for (int i=gid; i<8; i+=gsz){ float v;
        if (i==0) v=tof(sett2_b[0]); else if (i==1) v=tof(city2_b[0]);
        else if (i==2) v=tof(road2_b[0]); else v=tof(rob2_b[i-3]);
        pk[OFF_B2S+i]=v; }
    for (int i=gid; i<48; i+=gsz){ pk[OFF_LNW+i]=tof(ln_n_w[i]); pk[OFF_LNB+i]=tof(ln_n_b[i]); }
    for (int i=gid; i<122; i+=gsz){ int col = (i<5)? i : (280+i-5); pk[OFF_B2G+i]=tof(gfc2_b[col]); }
    for (int i=gid; i<80*80; i+=gsz){ int k=i/80, j=i%80; pk[OFF_WG1T+i]=tof(gfc1_w[j*80+k]); }
    for (int i=gid; i<80; i+=gsz) pk[OFF_B1G+i]=tof(gfc1_b[i]);
    for (int i=gid; i<80*122; i+=gsz){ int k=i/122, g=i-k*122;
        int col = (g<5)? g : (280+g-5);
        pk[OFF_WG2T+i]=tof(gfc2_w[col*PH+k]); }
}

__global__ void k_prep(P30 p, float* pk, const int* __restrict__ flag){
    if (*flag) prep_body<bf16>(p, pk); else prep_body<float>(p, pk);
}

// ---------------- K1: trunk layernorm + gfc1 (coalesced via Wg1T) ----------------
template<typename T>
__device__ __forceinline__ void tn_h_body(
        const T* __restrict__ trunk, const T* __restrict__ lw, const T* __restrict__ lb,
        const float* __restrict__ Wg1T, const float* __restrict__ b1g,
        float* __restrict__ tn_out, float* __restrict__ h_out, float (*s_tn)[TT]){
    int wave = threadIdx.x >> 6, lane = threadIdx.x & 63;
    int row  = blockIdx.x * 4 + wave;
    const T* tr = trunk + row * TT;
    float x0 = (lane < TT)      ? tof(tr[lane])      : 0.f;
    float x1 = (lane + 64 < TT) ? tof(tr[lane + 64]) : 0.f;
    float s = x0 + x1;
    for (int m = 32; m; m >>= 1) s += __shfl_xor(s, m, 64);
    float mu = s / TT;
    float d0 = (lane < TT)      ? (x0 - mu) : 0.f;
    float d1 = (lane + 64 < TT) ? (x1 - mu) : 0.f;
    float v = d0*d0 + d1*d1;
    for (int m = 32; m; m >>= 1) v += __shfl_xor(v, m, 64);
    float rstd = rsqrtf(v / TT + EPSF);
    if (lane < TT){
        float t = d0 * rstd * tof(lw[lane]) + tof(lb[lane]);
        s_tn[wave][lane] = t;
        tn_out[row*TT + lane] = t;
    }
    if (lane + 64 < TT){
        int i = lane + 64;
        float t = d1 * rstd * tof(lw[i]) + tof(lb[i]);
        s_tn[wave][i] = t;
        tn_out[row*TT + i] = t;
    }
    __syncthreads();
    for (int j = lane; j < PH; j += 64){
        float acc = b1g[j];
        #pragma unroll 8
        for (int k = 0; k < TT; ++k) acc += s_tn[wave][k] * Wg1T[k*PH + j];
        h_out[row*PH + j] = acc;
    }
}

__global__ __launch_bounds__(256) void k_tn_h(P30 p, const float* pk, float* tn_out,
                                              float* h_out, const int* __restrict__ flag){
    __shared__ float s_tn[4][TT];
    const float* Wg1T = pk + OFF_WG1T;
    const float* b1g  = pk + OFF_B1G;
    if (*flag)
        tn_h_body<bf16>((const bf16*)p.a[0], (const bf16*)p.a[4], (const bf16*)p.a[5],
                        Wg1T, b1g, tn_out, h_out, s_tn);
    else
        tn_h_body<float>((const float*)p.a[0], (const float*)p.a[4], (const float*)p.a[5],
                         Wg1T, b1g, tn_out, h_out, s_tn);
}

// ---------------- K2: batchnorm stats over B ----------------
template<typename T>
__device__ __forceinline__ void bnstats_body(
        const float* __restrict__ h, const T* __restrict__ bw, const T* __restrict__ bb,
        float* __restrict__ scale, float* __restrict__ shift){
    __shared__ float ss[256], sq[256];
    int f = blockIdx.x;
    float s = 0.f, q = 0.f;
    for (int b = threadIdx.x; b < BB; b += 256){
        float x = h[b*PH + f];
        s += x; q += x*x;
    }
    ss[threadIdx.x] = s; sq[threadIdx.x] = q;
    __syncthreads();
    for (int m = 128; m; m >>= 1){
        if ((int)threadIdx.x < m){
            ss[threadIdx.x] += ss[threadIdx.x + m];
            sq[threadIdx.x] += sq[threadIdx.x + m];
        }
        __syncthreads();
    }
    if (threadIdx.x == 0){
        float mu  = ss[0] / BB;
        float var = sq[0] / BB - mu*mu;
        float sc  = rsqrtf(var + EPSF) * tof(bw[f]);
        scale[f] = sc;
        shift[f] = tof(bb[f]) - mu * sc;
    }
}

__global__ __launch_bounds__(256) void k_bnstats(P30 p, const float* h,
                                                 float* scale, float* shift,
                                                 const int* __restrict__ flag){
    if (*flag) bnstats_body<bf16>(h, (const bf16*)p.a[10], (const bf16*)p.a[11], scale, shift);
    else       bnstats_body<float>(h, (const float*)p.a[10], (const float*)p.a[11], scale, shift);
}

// ---------------- K3: node LN + factored projections + all heads ----------------
// No shuffle-reductions anywhere; one output column per thread in stage 2.
struct HeadsSmem {
    float s_mish[PH];        // mish(bn(h)) for global head
    float s_nnT[HH*55];      // node LN transposed [h][n], pad 55 (gcd(55,32)=1)
    float s_te[HH*20];       // tile means [h][t2], pad 20
    float s_tp[128];         // tn-part proj + bias (sett|city|road|0)
    float s_rtp[32];         // robber tn-part + bias
    float s_trp[32*20];      // robber tile proj [k][t2]
    float s_np[128*57];      // node proj [j][n], pad 57 (gcd(57,32)=1)
};

template<typename T>
__device__ void heads_body(HeadsSmem& sm,
        const T* __restrict__ node_emb, const int* __restrict__ road_pairs,
        const int* __restrict__ tile_nodes,
        const float* __restrict__ tn_g, const float* __restrict__ hbuf,
        const float* __restrict__ scale, const float* __restrict__ shift,
        const float* __restrict__ pk, T* __restrict__ out){
    const float* WtT  = pk + OFF_WtT;
    const float* WnT  = pk + OFF_WnT;
    const float* b1p  = pk + OFF_B1P;
    const float* WrtT = pk + OFF_WRT;
    const float* Wrn  = pk + OFF_WRN;
    const float* rb1  = pk + OFF_RB1;
    const float* w2p  = pk + OFF_W2P;
    const float* rob2p= pk + OFF_ROB2;
    const float* b2s  = pk + OFF_B2S;
    const float* lnw  = pk + OFF_LNW;
    const float* lnb  = pk + OFF_LNB;
    const float* b2g  = pk + OFF_B2G;
    const float* wg2t = pk + OFF_WG2T;

    int row = blockIdx.x, tid = threadIdx.x;
    int wave = tid >> 6, lane = tid & 63;
    const float* tn_row = tn_g + row*TT;      // uniform base -> scalar loads

    // ---- phase 0: global-head mish + register-resident node LN ----
    if (tid < PH)
        sm.s_mish[tid] = mishf(hbuf[row*PH + tid] * scale[tid] + shift[tid]);
    if (wave == 3 && lane < NN){
        const T* ne = node_emb + ((size_t)row*NN + lane)*HH;
        float x[HH];
        #pragma unroll
        for (int i = 0; i < HH; ++i) x[i] = tof(ne[i]);
        float s = 0.f, q = 0.f;
        #pragma unroll
        for (int i = 0; i < HH; ++i){ s += x[i]; q += x[i]*x[i]; }
        float mu   = s * (1.f/HH);
        float var  = q * (1.f/HH) - mu*mu;
        float rstd = rsqrtf(fmaxf(var, 0.f) + EPSF);
        #pragma unroll
        for (int i = 0; i < HH; ++i)
            sm.s_nnT[i*55 + lane] = (x[i] - mu)*rstd*lnw[i] + lnb[i];
    }
    __syncthreads();

    // ---- phase 1: tn-part projections (scalar tn reads) + tile means ----
    if (tid < 128){
        int j = tid;
        float tp = b1p[j];
        #pragma unroll 4
        for (int k = 0; k < TT; ++k) tp += tn_row[k] * WtT[k*128 + j];
        sm.s_tp[j] = tp;
    } else if (tid < 160){
        int j = tid - 128;
        float rp = rb1[j];
        #pragma unroll 4
        for (int k = 0; k < TT; ++k) rp += tn_row[k] * WrtT[k*32 + j];
        sm.s_rtp[j] = rp;
    } else {
        for (int e = tid - 160; e < 912; e += 96){
            int h = e / 19, t2 = e - h*19;
            const int* tn6 = tile_nodes + t2*6;
            const float* r = sm.s_nnT + h*55;
            float s = r[tn6[0]] + r[tn6[1]] + r[tn6[2]]
                    + r[tn6[3]] + r[tn6[4]] + r[tn6[5]];
            sm.s_te[h*20 + t2] = s * (1.f/6.f);
        }
    }
    __syncthreads();

    // ---- phase 2: node-projection GEMM (scalar weights, 48 LDS reads/wave) ----
    {
        int j0 = __builtin_amdgcn_readfirstlane(wave << 5);   // wave's j-chunk
        const float* wb = WnT + j0;                            // SGPR base
        int nx = (lane < NN) ? lane : 0;
        float acc[32];
        #pragma unroll
        for (int j = 0; j < 32; ++j) acc[j] = 0.f;
        for (int h = 0; h < HH; ++h){
            float xn = sm.s_nnT[h*55 + nx];
            const float* wr = wb + h*128;
            #pragma unroll
            for (int j = 0; j < 32; ++j) acc[j] += wr[j] * xn;
        }
        if (lane < NN){
            #pragma unroll
            for (int j = 0; j < 32; ++j) sm.s_np[(j0 + j)*57 + lane] = acc[j];
        }
    }
    // robber tile projections (spread over all threads)
    for (int idx = tid; idx < 608; idx += 256){
        int k = idx & 31, t2 = idx >> 5;
        float acc2 = 0.f;
        #pragma unroll 4
        for (int h = 0; h < HH; ++h)
            acc2 += sm.s_te[h*20 + t2] * Wrn[h*32 + k];
        sm.s_trp[k*20 + t2] = acc2;
    }
    __syncthreads();

    // ---- stage 2: one output column per thread (no reductions) ----
    T* orow = out + (size_t)row*AA;
    for (int rnd = 0; rnd < 2; ++rnd){
        int c = tid + (rnd << 8);
        if (c >= 321) break;
        if (c < 54){
            int n = c;
            float acc = 0.f;
            #pragma unroll 4
            for (int k = 0; k < 32; ++k)
                acc += mishf(sm.s_tp[k] + sm.s_np[k*57 + n]) * w2p[k];
            stor(orow + 5 + n, acc + b2s[0]);
        } else if (c < 108){
            int n = c - 54;
            float acc = 0.f;
            #pragma unroll 4
            for (int k = 0; k < 32; ++k)
                acc += mishf(sm.s_tp[32+k] + sm.s_np[(32+k)*57 + n]) * w2p[32+k];
            stor(orow + 59 + n, acc + b2s[1]);
        } else if (c < 180){
            int r = c - 108;
            int srcn = road_pairs[2*r], dstn = road_pairs[2*r + 1];
            float acc = 0.f;
            #pragma unroll 4
            for (int k = 0; k < 32; ++k)
                acc += mishf(sm.s_tp[64+k] + sm.s_np[(64+k)*57 + srcn]
                                           + sm.s_np[(96+k)*57 + dstn]) * w2p[64+k];
            stor(orow + 113 + r, acc + b2s[2]);
        } else if (c < 199){
            int t2 = c - 180;
            float a0=0.f, a1=0.f, a2=0.f, a3=0.f, a4=0.f;
            #pragma unroll 4
            for (int k = 0; k < 32; ++k){
                float m = mishf(sm.s_rtp[k] + sm.s_trp[k*20 + t2]);
                a0 += m * rob2p[k];       a1 += m * rob2p[32+k];
                a2 += m * rob2p[64+k];    a3 += m * rob2p[96+k];
                a4 += m * rob2p[128+k];
            }
            stor(orow + 185 + t2*5 + 0, a0 + b2s[3]);
            stor(orow + 185 + t2*5 + 1, a1 + b2s[4]);
            stor(orow + 185 + t2*5 + 2, a2 + b2s[5]);
            stor(orow + 185 + t2*5 + 3, a3 + b2s[6]);
            stor(orow + 185 + t2*5 + 4, a4 + b2s[7]);
        } else {
            int g = c - 199;
            int col = (g < 5) ? g : (280 + g - 5);
            float acc = 0.f;
            #pragma unroll 4
            for (int k = 0; k < PH; ++k)
                acc += sm.s_mish[k] * wg2t[k*122 + g];
            stor(orow + col, acc + b2g[g]);
        }
    }
}

__global__ __launch_bounds__(256) void k_heads(P30 p, const float* tn_g, const float* hbuf,
                                               const float* scale, const float* shift,
                                               const float* pk, void* out,
                                               const int* __restrict__ flag){
    __shared__ HeadsSmem sm;
    if (*flag)
        heads_body<bf16>(sm, (const bf16*)p.a[1], (const int*)p.a[2], (const int*)p.a[3],
                         tn_g, hbuf, scale, shift, pk, (bf16*)out);
    else
        heads_body<float>(sm, (const float*)p.a[1], (const int*)p.a[2], (const int*)p.a[3],
                          tn_g, hbuf, scale, shift, pk, (float*)out);
}

extern "C" void kernel_launch(void* const* d_in, const int* in_sizes, int n_in,
                              void* d_out, int out_size, void* d_ws, size_t ws_size,
                              hipStream_t stream){
    P30 p;
    for (int i = 0; i < 30; ++i) p.a[i] = d_in[i];

    int*   flag  = (int*)d_ws;
    float* h     = (float*)((char*)d_ws + 256);     // B*PH floats
    float* tn    = h + (size_t)BB*PH;               // B*T floats
    float* scale = tn + (size_t)BB*TT;              // PH
    float* shift = scale + PH;                      // PH
    float* pk    = shift + PH;                      // PK_TOTAL floats of packed weights

    k_detect<<<1, 64, 0, stream>>>((const unsigned short*)d_in[0], flag);
    k_prep<<<64, 256, 0, stream>>>(p, pk, flag);
    k_tn_h<<<BB/4, 256, 0, stream>>>(p, pk, tn, h, flag);
    k_bnstats<<<PH, 256, 0, stream>>>(p, h, scale, shift, flag);
    k_heads<<<BB, 256, 0, stream>>>(p, tn, h, scale, shift, pk, d_out, flag);
}

// Round 4
// 1259.729 us; speedup vs baseline: 4.2815x; 1.0725x over previous
//
#include <hip/hip_runtime.h>
#include <hip/hip_bf16.h>

#define BB 16384
#define NN 54
#define TT 80
#define HH 48
#define PH 80
#define SHH 32
#define AA 397
#define EPSF 1e-5f

typedef __hip_bfloat16 bf16;

__device__ __forceinline__ float tof(float x){ return x; }
__device__ __forceinline__ float tof(bf16 x){ return __bfloat162float(x); }
__device__ __forceinline__ void stor(float* p, float v){ *p = v; }
__device__ __forceinline__ void stor(bf16* p, float v){ *p = __float2bfloat16(v); }

// mish(x) = x * tanh(softplus(x)) = x * w/(w+2), w = e*(2+e), e = exp(x)
__device__ __forceinline__ float mishf(float x){
    float e = __expf(fminf(x, 15.f));
    float w = e * (2.f + e);
    return x * w / (w + 2.f);
}

// unpack 2 bf16 packed in a u32 -> 2 floats
__device__ __forceinline__ void unpack2(unsigned u, float* x){
    x[0] = __uint_as_float(u << 16);
    x[1] = __uint_as_float(u & 0xffff0000u);
}

struct P30 { const void* a[30]; };

// ---- packed-weight workspace layout (fp32 element offsets) ----
#define OFF_WtT   0                     // [80][128] tn-part weights: sett|city|road|0
#define OFF_WnT   (OFF_WtT + 80*128)    // [48][128] node-part: sett|city|road_src|road_dst
#define OFF_B1P   (OFF_WnT + 48*128)    // [128] layer-1 biases (dst cols = 0)
#define OFF_WRT   (OFF_B1P + 128)       // [80][32] robber tn-part
#define OFF_WRN   (OFF_WRT + 80*32)     // [48][32] robber tile-part
#define OFF_RB1   (OFF_WRN + 48*32)     // [32] rob1_b
#define OFF_W2P   (OFF_RB1 + 32)        // [96] sett2_w|city2_w|road2_w
#define OFF_ROB2  (OFF_W2P + 96)        // [5][32] rob2_w
#define OFF_B2S   (OFF_ROB2 + 160)      // [8] sett2_b,city2_b,road2_b,rob2_b[5]
#define OFF_LNW   (OFF_B2S + 8)         // [48] ln_n_w
#define OFF_LNB   (OFF_LNW + 48)        // [48] ln_n_b
#define OFF_B2G   (OFF_LNB + 48)        // [122] gfc2_b at surviving cols
#define OFF_WG1T  (OFF_B2G + 122)       // [80][80] gfc1_w transposed
#define OFF_B1G   (OFF_WG1T + 80*80)    // [80] gfc1_b
#define OFF_WG2T  (OFF_B1G + 80)        // [80][122] gfc2_w transposed, surviving cols
#define PK_TOTAL  (OFF_WG2T + 80*122)

// Runtime dtype probe + zero the batchnorm accumulators
__global__ void k_detect(const unsigned short* tr, int* flag,
                         float* bn_sum, float* bn_sq){
    int t = threadIdx.x;
    if (t < PH){ bn_sum[t] = 0.f; bn_sq[t] = 0.f; }
    if (t == 0){
        int good = 0;
        for (int i = 0; i < 1024; i += 2){
            int e = (tr[i] >> 7) & 0xFF;
            if (e >= 117 && e <= 137) good++;
        }
        *flag = (good > 256) ? 1 : 0;   // 1 = bf16, 0 = float32
    }
}

// ---------------- K0: pack/transpose all head weights to fp32 ----------------
template<typename T>
__device__ void prep_body(P30 p, float* pk){
    const T* sett1_w=(const T*)p.a[14]; const T* sett1_b=(const T*)p.a[15];
    const T* sett2_w=(const T*)p.a[16]; const T* sett2_b=(const T*)p.a[17];
    const T* city1_w=(const T*)p.a[18]; const T* city1_b=(const T*)p.a[19];
    const T* city2_w=(const T*)p.a[20]; const T* city2_b=(const T*)p.a[21];
    const T* road1_w=(const T*)p.a[22]; const T* road1_b=(const T*)p.a[23];
    const T* road2_w=(const T*)p.a[24]; const T* road2_b=(const T*)p.a[25];
    const T* rob1_w =(const T*)p.a[26]; const T* rob1_b =(const T*)p.a[27];
    const T* rob2_w =(const T*)p.a[28]; const T* rob2_b =(const T*)p.a[29];
    const T* gfc1_w =(const T*)p.a[8];  const T* gfc1_b =(const T*)p.a[9];
    const T* gfc2_w =(const T*)p.a[12]; const T* gfc2_b =(const T*)p.a[13];
    const T* ln_n_w =(const T*)p.a[6];  const T* ln_n_b =(const T*)p.a[7];

    int gid = blockIdx.x*blockDim.x + threadIdx.x;
    int gsz = gridDim.x*blockDim.x;

    for (int i=gid; i<80*128; i+=gsz){ int k=i>>7, j=i&127; float v;
        if (j<32)      v = tof(sett1_w[j*128+k]);
        else if (j<64) v = tof(city1_w[(j-32)*128+k]);
        else if (j<96) v = tof(road1_w[(j-64)*176+k]);
        else           v = 0.f;
        pk[OFF_WtT+i]=v; }
    for (int i=gid; i<48*128; i+=gsz){ int k=i>>7, j=i&127; float v;
        if (j<32)      v = tof(sett1_w[j*128+80+k]);
        else if (j<64) v = tof(city1_w[(j-32)*128+80+k]);
        else if (j<96) v = tof(road1_w[(j-64)*176+80+k]);
        else           v = tof(road1_w[(j-96)*176+128+k]);
        pk[OFF_WnT+i]=v; }
    for (int i=gid; i<128; i+=gsz){ float v;
        if (i<32) v=tof(sett1_b[i]); else if (i<64) v=tof(city1_b[i-32]);
        else if (i<96) v=tof(road1_b[i-64]); else v=0.f;
        pk[OFF_B1P+i]=v; }
    for (int i=gid; i<80*32; i+=gsz){ int k=i>>5, h=i&31; pk[OFF_WRT+i]=tof(rob1_w[h*128+k]); }
    for (int i=gid; i<48*32; i+=gsz){ int k=i>>5, h=i&31; pk[OFF_WRN+i]=tof(rob1_w[h*128+80+k]); }
    for (int i=gid; i<32; i+=gsz) pk[OFF_RB1+i]=tof(rob1_b[i]);
    for (int i=gid; i<96; i+=gsz){ float v;
        if (i<32) v=tof(sett2_w[i]); else if (i<64) v=tof(city2_w[i-32]); else v=tof(road2_w[i-64]);
        pk[OFF_W2P+i]=v; }
    for (int i=gid; i<160; i+=gsz) pk[OFF_ROB2+i]=tof(rob2_w[i]);
    for (int i=gid; i<8; i+=gsz){ float v;
        if (i==0) v=tof(sett2_b[0]); else if (i==1) v=tof(city2_b[0]);
        else if (i==2) v=tof(road2_b[0]); else v=tof(rob2_b[i-3]);
        pk[OFF_B2S+i]=v; }
    for (int i=gid; i<48; i+=gsz){ pk[OFF_LNW+i]=tof(ln_n_w[i]); pk[OFF_LNB+i]=tof(ln_n_b[i]); }
    for (int i=gid; i<122; i+=gsz){ int col = (i<5)? i : (280+i-5); pk[OFF_B2G+i]=tof(gfc2_b[col]); }
    for (int i=gid; i<80*80; i+=gsz){ int k=i/80, j=i%80; pk[OFF_WG1T+i]=tof(gfc1_w[j*80+k]); }
    for (int i=gid; i<80; i+=gsz) pk[OFF_B1G+i]=tof(gfc1_b[i]);
    for (int i=gid; i<80*122; i+=gsz){ int k=i/122, g=i-k*122;
        int col = (g<5)? g : (280+g-5);
        pk[OFF_WG2T+i]=tof(gfc2_w[col*PH+k]); }
}

__global__ void k_prep(P30 p, float* pk, const int* __restrict__ flag){
    if (*flag) prep_body<bf16>(p, pk); else prep_body<float>(p, pk);
}

// ---------------- K1: 8-row batch: trunk LN + [gfc1 | tp | rtp] GEMM ----------------
// thread j owns output col j for all 8 rows: 1 weight load -> 8 FMA.
template<typename T>
__device__ void tn8_body(const T* __restrict__ trunk,
                         const T* __restrict__ lw, const T* __restrict__ lb,
                         const float* __restrict__ pk,
                         float* __restrict__ hbuf, float* __restrict__ tpr,
                         float* __restrict__ bn_sum, float* __restrict__ bn_sq,
                         float* __restrict__ s_tnT){   // [80][12]
    int tid = threadIdx.x, wave = tid >> 6, lane = tid & 63;
    int row0 = blockIdx.x * 8;
    // LN: wave w handles rows 2w, 2w+1 (classic shuffle LN over 80 cols)
    for (int r2 = 0; r2 < 2; ++r2){
        int rb = wave*2 + r2;
        const T* tr = trunk + (size_t)(row0 + rb) * TT;
        float x0 = (lane < TT)      ? tof(tr[lane])      : 0.f;
        float x1 = (lane + 64 < TT) ? tof(tr[lane + 64]) : 0.f;
        float s = x0 + x1;
        for (int m = 32; m; m >>= 1) s += __shfl_xor(s, m, 64);
        float mu = s / TT;
        float d0 = (lane < TT)      ? (x0 - mu) : 0.f;
        float d1 = (lane + 64 < TT) ? (x1 - mu) : 0.f;
        float v = d0*d0 + d1*d1;
        for (int m = 32; m; m >>= 1) v += __shfl_xor(v, m, 64);
        float rstd = rsqrtf(v / TT + EPSF);
        if (lane < TT)
            s_tnT[lane*12 + rb] = d0 * rstd * tof(lw[lane]) + tof(lb[lane]);
        if (lane + 64 < TT)
            s_tnT[(lane+64)*12 + rb] = d1 * rstd * tof(lw[lane+64]) + tof(lb[lane+64]);
    }
    __syncthreads();
    if (tid < 240){
        const float* wp; int stride; float bias; float* ob; int ostride;
        if (tid < 80){
            wp = pk + OFF_WG1T + tid; stride = 80;  bias = pk[OFF_B1G + tid];
            ob = hbuf + (size_t)row0*80 + tid;  ostride = 80;
        } else if (tid < 208){
            int j = tid - 80;
            wp = pk + OFF_WtT + j;  stride = 128; bias = pk[OFF_B1P + j];
            ob = tpr + (size_t)row0*160 + j;    ostride = 160;
        } else {
            int j = tid - 208;
            wp = pk + OFF_WRT + j;  stride = 32;  bias = pk[OFF_RB1 + j];
            ob = tpr + (size_t)row0*160 + 128 + j; ostride = 160;
        }
        float acc[8];
        #pragma unroll
        for (int r = 0; r < 8; ++r) acc[r] = bias;
        #pragma unroll 4
        for (int k = 0; k < TT; ++k){
            float wv = wp[k*stride];
            float4 a = *(const float4*)&s_tnT[k*12];
            float4 b = *(const float4*)&s_tnT[k*12 + 4];
            acc[0] += wv*a.x; acc[1] += wv*a.y; acc[2] += wv*a.z; acc[3] += wv*a.w;
            acc[4] += wv*b.x; acc[5] += wv*b.y; acc[6] += wv*b.z; acc[7] += wv*b.w;
        }
        #pragma unroll
        for (int r = 0; r < 8; ++r) ob[r*ostride] = acc[r];
        if (tid < 80){
            float s8 = 0.f, q8 = 0.f;
            #pragma unroll
            for (int r = 0; r < 8; ++r){ s8 += acc[r]; q8 += acc[r]*acc[r]; }
            atomicAdd(bn_sum + tid, s8);
            atomicAdd(bn_sq  + tid, q8);
        }
    }
}

__global__ __launch_bounds__(256) void k_tn8(P30 p, const float* pk, float* hbuf,
                                             float* tpr, float* bn_sum, float* bn_sq,
                                             const int* __restrict__ flag){
    __shared__ float s_tnT[80*12];
    if (*flag)
        tn8_body<bf16>((const bf16*)p.a[0], (const bf16*)p.a[4], (const bf16*)p.a[5],
                       pk, hbuf, tpr, bn_sum, bn_sq, s_tnT);
    else
        tn8_body<float>((const float*)p.a[0], (const float*)p.a[4], (const float*)p.a[5],
                        pk, hbuf, tpr, bn_sum, bn_sq, s_tnT);
}

// ---------------- K2: batchnorm scale/shift from accumulated sums ----------------
__global__ void k_bnstats2(P30 p, const float* __restrict__ bn_sum,
                           const float* __restrict__ bn_sq,
                           float* scale, float* shift, const int* __restrict__ flag){
    int f = threadIdx.x;
    if (f < PH){
        float mu  = bn_sum[f] * (1.f/BB);
        float var = bn_sq[f]  * (1.f/BB) - mu*mu;
        float bw, bb;
        if (*flag){ bw = tof(((const bf16*)p.a[10])[f]); bb = tof(((const bf16*)p.a[11])[f]); }
        else      { bw = ((const float*)p.a[10])[f];     bb = ((const float*)p.a[11])[f]; }
        float sc = rsqrtf(var + EPSF) * bw;
        scale[f] = sc;
        shift[f] = bb - mu * sc;
    }
}

// ---------------- K3: global head, 16 rows per block ----------------
template<typename T>
__device__ void ghead_body(const float* __restrict__ hbuf,
                           const float* __restrict__ scale, const float* __restrict__ shift,
                           const float* __restrict__ pk, T* __restrict__ out,
                           float* __restrict__ s_mT){   // [80][20]
    int tid = threadIdx.x;
    int row0 = blockIdx.x * 16;
    const float* wg2t = pk + OFF_WG2T;
    const float* b2g  = pk + OFF_B2G;
    for (int i = tid; i < 1280; i += 256){
        int r = i / 80, k = i - r*80;
        float hv = hbuf[(size_t)(row0 + r)*80 + k];
        s_mT[k*20 + r] = mishf(hv * scale[k] + shift[k]);
    }
    __syncthreads();
    int g = tid & 127, half = tid >> 7, r0 = half * 8;
    if (g < 122){
        float acc[8] = {0,0,0,0,0,0,0,0};
        #pragma unroll 4
        for (int k = 0; k < 80; ++k){
            float wv = wg2t[k*122 + g];
            float4 a = *(const float4*)&s_mT[k*20 + r0];
            float4 b = *(const float4*)&s_mT[k*20 + r0 + 4];
            acc[0] += wv*a.x; acc[1] += wv*a.y; acc[2] += wv*a.z; acc[3] += wv*a.w;
            acc[4] += wv*b.x; acc[5] += wv*b.y; acc[6] += wv*b.z; acc[7] += wv*b.w;
        }
        int col = (g < 5) ? g : (280 + g - 5);
        float bg = b2g[g];
        #pragma unroll
        for (int r = 0; r < 8; ++r)
            stor(out + (size_t)(row0 + r0 + r)*AA + col, acc[r] + bg);
    }
}

__global__ __launch_bounds__(256) void k_ghead(const float* hbuf, const float* scale,
                                               const float* shift, const float* pk,
                                               void* out, const int* __restrict__ flag){
    __shared__ float s_mT[80*20];
    if (*flag) ghead_body<bf16>(hbuf, scale, shift, pk, (bf16*)out, s_mT);
    else       ghead_body<float>(hbuf, scale, shift, pk, (float*)out, s_mT);
}

// ---------------- K4: node LN + register-resident proj + small heads ----------------
struct HeadsSmem {
    float s_nnT[HH*55];     // node LN transposed [h][n]
    float s_npr[64*56];     // road src (k 0..31) / dst (k 32..63) proj chunks [k][n]
    float s_te[HH*20];      // tile means [h][t2]
    float s_trp[32*20];     // robber tile proj [k][t2]
};

template<typename T>
__device__ void heads_body(HeadsSmem& sm,
        const T* __restrict__ node_emb, const int* __restrict__ road_pairs,
        const int* __restrict__ tile_nodes,
        const float* __restrict__ tpr, const float* __restrict__ pk,
        T* __restrict__ out){
    const float* WnT   = pk + OFF_WnT;
    const float* Wrn   = pk + OFF_WRN;
    const float* w2p   = pk + OFF_W2P;
    const float* rob2p = pk + OFF_ROB2;
    const float* b2s   = pk + OFF_B2S;
    const float* lnw   = pk + OFF_LNW;
    const float* lnb   = pk + OFF_LNB;

    int row = blockIdx.x, tid = threadIdx.x;
    int wave = tid >> 6, lane = tid & 63;
    const float* tpr_row = tpr + (size_t)row*160;

    // ---- phase 0: node LN, 16 nodes per wave, one node per lane, vectorized loads ----
    if (lane < 16){
        int n = (wave << 4) + lane;
        if (n < NN){
            const T* ne = node_emb + ((size_t)row*NN + n)*HH;
            float x[HH];
            if constexpr (sizeof(T) == 2){
                const uint4* v = (const uint4*)ne;   // 48 bf16 = 6 x 16B
                #pragma unroll
                for (int i = 0; i < 6; ++i){
                    uint4 u = v[i];
                    unpack2(u.x, x + i*8 + 0); unpack2(u.y, x + i*8 + 2);
                    unpack2(u.z, x + i*8 + 4); unpack2(u.w, x + i*8 + 6);
                }
            } else {
                const float4* v = (const float4*)ne;  // 48 f32 = 12 x 16B
                #pragma unroll
                for (int i = 0; i < 12; ++i){
                    float4 f = v[i];
                    x[i*4] = f.x; x[i*4+1] = f.y; x[i*4+2] = f.z; x[i*4+3] = f.w;
                }
            }
            float s = 0.f, q = 0.f;
            #pragma unroll
            for (int i = 0; i < HH; ++i){ s += x[i]; q += x[i]*x[i]; }
            float mu   = s * (1.f/HH);
            float var  = q * (1.f/HH) - mu*mu;
            float rstd = rsqrtf(fmaxf(var, 0.f) + EPSF);
            #pragma unroll
            for (int i = 0; i < HH; ++i)
                sm.s_nnT[i*55 + n] = (x[i] - mu)*rstd*lnw[i] + lnb[i];
        }
    }
    __syncthreads();

    // ---- phase 1: proj GEMM in registers (wave owns j-chunk, lane owns node) ----
    int j0 = __builtin_amdgcn_readfirstlane(wave << 5);
    int nx = (lane < NN) ? lane : (NN-1);
    float acc[32];
    #pragma unroll
    for (int j = 0; j < 32; ++j) acc[j] = 0.f;
    const float* wbase = WnT + j0;                 // uniform -> scalar loads
    #pragma unroll 2
    for (int h = 0; h < HH; ++h){
        float xn = sm.s_nnT[h*55 + nx];
        const float* wr = wbase + h*128;
        #pragma unroll
        for (int j = 0; j < 32; ++j) acc[j] += wr[j] * xn;
    }
    T* orow = out + (size_t)row*AA;
    if (wave < 2){
        // sett (wave 0) / city (wave 1): finish fully in registers, store directly
        if (lane < NN){
            const float* tpk = tpr_row + j0;       // uniform
            float o = b2s[wave];
            #pragma unroll 4
            for (int k = 0; k < 32; ++k)
                o += mishf(tpk[k] + acc[k]) * w2p[j0 + k];
            stor(orow + (wave ? 59 : 5) + lane, o);
        }
    } else {
        // road src/dst chunks to LDS for cross-node mixing
        if (lane < NN){
            int kb = (wave - 2) << 5;
            #pragma unroll
            for (int k = 0; k < 32; ++k) sm.s_npr[(kb + k)*56 + lane] = acc[k];
        }
    }
    __syncthreads();

    // ---- phase 2: tile means ----
    for (int i = tid; i < 912; i += 256){          // 48*19
        int h = i / 19, t2 = i - h*19;
        const int* t6 = tile_nodes + t2*6;
        const float* r = sm.s_nnT + h*55;
        sm.s_te[h*20 + t2] = (r[t6[0]] + r[t6[1]] + r[t6[2]]
                            + r[t6[3]] + r[t6[4]] + r[t6[5]]) * (1.f/6.f);
    }
    __syncthreads();

    // ---- phase 3: robber tile proj ----
    for (int idx = tid; idx < 608; idx += 256){    // 32*19
        int k = idx & 31, t2 = idx >> 5;
        float a2 = 0.f;
        #pragma unroll 4
        for (int h = 0; h < HH; ++h)
            a2 += sm.s_te[h*20 + t2] * Wrn[h*32 + k];
        sm.s_trp[k*20 + t2] = a2;
    }
    __syncthreads();

    // ---- phase 4: roads + robber ----
    if (tid < 72){
        int r = tid;
        int srcn = road_pairs[2*r], dstn = road_pairs[2*r + 1];
        const float* tpk = tpr_row + 64;           // uniform
        float o = b2s[2];
        #pragma unroll 4
        for (int k = 0; k < 32; ++k)
            o += mishf(tpk[k] + sm.s_npr[k*56 + srcn]
                              + sm.s_npr[(32 + k)*56 + dstn]) * w2p[64 + k];
        stor(orow + 113 + r, o);
    } else if (tid >= 128 && tid < 147){
        int t2 = tid - 128;
        const float* rtp = tpr_row + 128;          // uniform
        float a0 = b2s[3], a1 = b2s[4], a2 = b2s[5], a3 = b2s[6], a4 = b2s[7];
        #pragma unroll 2
        for (int k = 0; k < 32; ++k){
            float m = mishf(rtp[k] + sm.s_trp[k*20 + t2]);
            a0 += m * rob2p[k];      a1 += m * rob2p[32 + k];
            a2 += m * rob2p[64 + k]; a3 += m * rob2p[96 + k];
            a4 += m * rob2p[128 + k];
        }
        stor(orow + 185 + t2*5 + 0, a0);
        stor(orow + 185 + t2*5 + 1, a1);
        stor(orow + 185 + t2*5 + 2, a2);
        stor(orow + 185 + t2*5 + 3, a3);
        stor(orow + 185 + t2*5 + 4, a4);
    }
}

__global__ __launch_bounds__(256) void k_heads(P30 p, const float* tpr, const float* pk,
                                               void* out, const int* __restrict__ flag){
    __shared__ HeadsSmem sm;
    if (*flag)
        heads_body<bf16>(sm, (const bf16*)p.a[1], (const int*)p.a[2], (const int*)p.a[3],
                         tpr, pk, (bf16*)out);
    else
        heads_body<float>(sm, (const float*)p.a[1], (const int*)p.a[2], (const int*)p.a[3],
                          tpr, pk, (float*)out);
}

extern "C" void kernel_launch(void* const* d_in, const int* in_sizes, int n_in,
                              void* d_out, int out_size, void* d_ws, size_t ws_size,
                              hipStream_t stream){
    P30 p;
    for (int i = 0; i < 30; ++i) p.a[i] = d_in[i];

    int*   flag   = (int*)d_ws;
    float* bn_sum = (float*)((char*)d_ws + 256);        // 80
    float* bn_sq  = bn_sum + PH;                        // 80
    float* scale  = bn_sq + PH;                         // 80
    float* shift  = scale + PH;                         // 80
    float* hbuf   = (float*)((char*)d_ws + 2048);       // BB*80
    float* tpr    = hbuf + (size_t)BB*PH;               // BB*160
    float* pk     = tpr + (size_t)BB*160;               // PK_TOTAL packed weights

    k_detect<<<1, 128, 0, stream>>>((const unsigned short*)d_in[0], flag, bn_sum, bn_sq);
    k_prep<<<64, 256, 0, stream>>>(p, pk, flag);
    k_tn8<<<BB/8, 256, 0, stream>>>(p, pk, hbuf, tpr, bn_sum, bn_sq, flag);
    k_bnstats2<<<1, 128, 0, stream>>>(p, bn_sum, bn_sq, scale, shift, flag);
    k_ghead<<<BB/16, 256, 0, stream>>>(hbuf, scale, shift, pk, d_out, flag);
    k_heads<<<BB, 256, 0, stream>>>(p, tpr, pk, d_out, flag);
}